// Round 3
// baseline (1189.278 us; speedup 1.0000x reference)
//
#include <hip/hip_runtime.h>
#include <hip/hip_bf16.h>

typedef unsigned int uint;
typedef unsigned short u16;
typedef unsigned long long u64;

#define N_NODES 8192
#define IN_F    512
#define OUT_F   64
#define CHEADS  2
#define ROWS    (N_NODES * CHEADS)   // 16384
#define ROW_LEN N_NODES              // 8192
#define BLK     256
#define PER_TH  (ROW_LEN / BLK)      // 32 elements per thread
#define VCHUNKS (PER_TH / 4)         // 8 x float4 per thread
#define CAND_CAP 2048
#define SEL_CAP  64

__device__ __forceinline__ float bits_to_float(uint u) {
    union { uint u; float f; } cv; cv.u = u; return cv.f;
}
__device__ __forceinline__ uint float_to_bits(float f) {
    union { uint u; float f; } cv; cv.f = f; return cv.u;
}
// order-preserving fp32 bits -> uint transform
__device__ __forceinline__ uint sortable32(uint u) {
    return u ^ ((u & 0x80000000u) ? 0xFFFFFFFFu : 0x80000000u);
}
__device__ __forceinline__ uint unsortable32(uint s) {
    return (s & 0x80000000u) ? (s ^ 0x80000000u) : ~s;
}
__device__ __forceinline__ float key_to_val(uint key) {
    return bits_to_float(unsortable32(key));
}

// Defensive decode of the scalar k (int32 / int64 / bf16 / fp32 all -> 32)
__device__ __forceinline__ int decode_k(const void* p) {
    int ki = *(const int*)p;
    if (ki >= 1 && ki <= ROW_LEN) return ki;
    {
        uint b = *(const u16*)p;
        float f = bits_to_float(b << 16);
        int kf = (int)f;
        if (f == (float)kf && kf >= 1 && kf <= ROW_LEN) return kf;
    }
    {
        float g = *(const float*)p;
        int kg = (int)g;
        if (g == (float)kg && kg >= 1 && kg <= ROW_LEN) return kg;
    }
    return 32;
}

// -------- kernel 1: h = x @ W^T  (fp32) --------
// one wave per output row n; lane f computes h[n][f] over K=512
__global__ __launch_bounds__(BLK) void h_kernel(
    const float* __restrict__ x, const float* __restrict__ W, float* __restrict__ hbuf)
{
    const int f = threadIdx.x & 63;
    const int n = (blockIdx.x << 2) + (threadIdx.x >> 6);
    const float* xr = x + (size_t)n * IN_F;
    const float* wr = W + (size_t)f * IN_F;
    float acc = 0.f;
    #pragma unroll 4
    for (int kk = 0; kk < IN_F; kk += 4) {
        float4 xa = *reinterpret_cast<const float4*>(xr + kk);
        float4 wa = *reinterpret_cast<const float4*>(wr + kk);
        acc = fmaf(xa.x, wa.x, acc);
        acc = fmaf(xa.y, wa.y, acc);
        acc = fmaf(xa.z, wa.z, acc);
        acc = fmaf(xa.w, wa.w, acc);
    }
    hbuf[(size_t)n * OUT_F + f] = acc;
}

// -------- kernel 2: per-row exact top-k + softmax + spmm + dense att write --------
__global__ __launch_bounds__(BLK) void topk_kernel(
    const float* __restrict__ attn,
    const float* __restrict__ hbuf,
    const void* __restrict__ kptr,
    float* __restrict__ outp,      // [N][C*OUT_F]
    float* __restrict__ att_out)   // [ROWS][ROW_LEN]
{
    __shared__ uint  s_lmax[BLK];
    __shared__ uint  s_ck[CAND_CAP];     // candidate sortable keys
    __shared__ u16   s_cidx[CAND_CAP];   // candidate indices
    __shared__ int   s_sel_idx[SEL_CAP];
    __shared__ float s_sel_w[SEL_CAP];
    __shared__ float s_lsum[4];
    __shared__ uint  s_bc[4];            // [0]=pivot p, [1]=max key, [2]=V32, [3]=Tlow
    __shared__ int   s_cnt[2];

    const int tid = threadIdx.x;
    const int row = blockIdx.x;
    const int k   = decode_k(kptr);   // 32

    if (tid == 0) { s_cnt[0] = 0; s_cnt[1] = 0; }

    const float* rowp = attn + (size_t)row * ROW_LEN;

    // phase 0: load row (fp32) into registers as sortable keys; per-thread max
    uint lk[PER_TH];
    uint lmax = 0;
    #pragma unroll
    for (int c = 0; c < VCHUNKS; ++c) {
        const int base = (c * BLK + tid) * 4;
        float4 v = *reinterpret_cast<const float4*>(rowp + base);
        const uint k0 = sortable32(float_to_bits(v.x));
        const uint k1 = sortable32(float_to_bits(v.y));
        const uint k2 = sortable32(float_to_bits(v.z));
        const uint k3 = sortable32(float_to_bits(v.w));
        lk[c * 4 + 0] = k0; lk[c * 4 + 1] = k1;
        lk[c * 4 + 2] = k2; lk[c * 4 + 3] = k3;
        lmax = max(max(max(lmax, k0), max(k1, k2)), k3);
    }
    s_lmax[tid] = lmax;
    __syncthreads();

    // phase 1 (wave 0): p = k-th largest of 256 thread-maxima (lower bound of V_k);
    // also the global max key
    if (tid < 64) {
        uint a0 = s_lmax[tid], a1 = s_lmax[tid + 64], a2 = s_lmax[tid + 128], a3 = s_lmax[tid + 192];
        uint mk = max(max(a0, a1), max(a2, a3));
        #pragma unroll
        for (int off = 1; off < 64; off <<= 1)
            mk = max(mk, (uint)__shfl_xor((int)mk, off, 64));
        uint lo = 0u, hi = 0xFFFFFFFFu;
        while (lo < hi) {
            const uint d = hi - lo;
            const uint mid = lo + (d >> 1) + (d & 1u);   // upper mid
            int c = (a0 >= mid) + (a1 >= mid) + (a2 >= mid) + (a3 >= mid);
            #pragma unroll
            for (int off = 1; off < 64; off <<= 1) c += __shfl_xor(c, off, 64);
            if (c >= k) lo = mid; else hi = mid - 1;
        }
        if (tid == 0) { s_bc[0] = lo; s_bc[1] = mk; }
    }
    __syncthreads();
    const uint p = s_bc[0];

    // phase 2: compact candidates (keys >= p); expected ~k+few
    #pragma unroll
    for (int e = 0; e < PER_TH; ++e) {
        if (lk[e] >= p) {
            int pos = atomicAdd(&s_cnt[0], 1);
            if (pos < CAND_CAP) {
                const int c = e >> 2, j = e & 3;
                s_ck[pos]   = lk[e];
                s_cidx[pos] = (u16)((c * BLK + tid) * 4 + j);
            }
        }
    }
    __syncthreads();

    // phase 3 (wave 0): exact k-th value V32; tie-break threshold Tlow on index
    if (tid < 64) {
        int cnt = s_cnt[0];
        if (cnt > CAND_CAP) cnt = CAND_CAP;
        // V32 = largest V with count(key >= V) >= k
        uint lo = p, hi = 0xFFFFFFFFu;
        while (lo < hi) {
            const uint d = hi - lo;
            const uint mid = lo + (d >> 1) + (d & 1u);
            int c = 0;
            for (int j = tid; j < cnt; j += 64) c += (s_ck[j] >= mid) ? 1 : 0;
            #pragma unroll
            for (int off = 1; off < 64; off <<= 1) c += __shfl_xor(c, off, 64);
            if (c >= k) lo = mid; else hi = mid - 1;
        }
        const uint V32 = lo;
        // g = count(key > V32)
        int g = 0;
        for (int j = tid; j < cnt; j += 64) g += (s_ck[j] > V32) ? 1 : 0;
        #pragma unroll
        for (int off = 1; off < 64; off <<= 1) g += __shfl_xor(g, off, 64);
        const int e_need = k - g;   // >= 1
        // Tlow = e_need-th largest of (0x1FFF ^ idx) among keys == V32
        uint tlo = 0u, thi = 0x1FFFu;
        while (tlo < thi) {
            const uint d = thi - tlo;
            const uint mid = tlo + (d >> 1) + (d & 1u);
            int c = 0;
            for (int j = tid; j < cnt; j += 64)
                c += (s_ck[j] == V32 && (0x1FFFu ^ (uint)s_cidx[j]) >= mid) ? 1 : 0;
            #pragma unroll
            for (int off = 1; off < 64; off <<= 1) c += __shfl_xor(c, off, 64);
            if (c >= e_need) tlo = mid; else thi = mid - 1;
        }
        if (tid == 0) { s_bc[2] = V32; s_bc[3] = tlo; }
    }
    __syncthreads();
    const uint  V32  = s_bc[2];
    const uint  Tlow = s_bc[3];
    const float m    = key_to_val(s_bc[1]);   // row max value

    // phase 4: weights for selected, local softmax-denominator sum
    float lsum = 0.f;
    #pragma unroll
    for (int e = 0; e < PER_TH; ++e) {
        const int idx = ((e >> 2) * BLK + tid) * 4 + (e & 3);
        const bool sel = (lk[e] > V32) || (lk[e] == V32 && (0x1FFFu ^ (uint)idx) >= Tlow);
        if (sel) {
            const float v = key_to_val(lk[e]);
            const float w = __expf(v - m);
            lsum += w;
            int pos = atomicAdd(&s_cnt[1], 1);
            if (pos < SEL_CAP) {
                s_sel_idx[pos] = idx;
                s_sel_w[pos]   = w;
            }
        }
    }
    #pragma unroll
    for (int off = 1; off < 64; off <<= 1) lsum += __shfl_xor(lsum, off, 64);
    if ((tid & 63) == 0) s_lsum[tid >> 6] = lsum;
    __syncthreads();
    const float l     = s_lsum[0] + s_lsum[1] + s_lsum[2] + s_lsum[3];
    const float inv_l = (l > 0.f) ? (1.0f / l) : 0.f;

    // phase 5: h_prime row (sparse gather) -> out, interleaved layout
    const int n  = row & (N_NODES - 1);
    const int ch = row >> 13;
    if (tid < OUT_F) {
        const int scnt = min(s_cnt[1], SEL_CAP);
        float acc = 0.f;
        for (int j = 0; j < scnt; ++j)
            acc += s_sel_w[j] * hbuf[(size_t)s_sel_idx[j] * OUT_F + tid];
        outp[(size_t)n * (CHEADS * OUT_F) + ch * OUT_F + tid] = acc * inv_l;
    }

    // phase 5b: write dense att row (zeros except selected)
    float* orow = att_out + (size_t)row * ROW_LEN;
    #pragma unroll
    for (int c = 0; c < VCHUNKS; ++c) {
        const int base = (c * BLK + tid) * 4;
        float4 st;
        float* stp = &st.x;
        #pragma unroll
        for (int j = 0; j < 4; ++j) {
            const int e = c * 4 + j;
            const int idx = base + j;
            const bool sel = (lk[e] > V32) || (lk[e] == V32 && (0x1FFFu ^ (uint)idx) >= Tlow);
            stp[j] = sel ? (__expf(key_to_val(lk[e]) - m) * inv_l) : 0.f;
        }
        *reinterpret_cast<float4*>(orow + base) = st;
    }
}

extern "C" void kernel_launch(void* const* d_in, const int* in_sizes, int n_in,
                              void* d_out, int out_size, void* d_ws, size_t ws_size,
                              hipStream_t stream) {
    const float* x    = (const float*)d_in[0];
    const float* W    = (const float*)d_in[1];
    const float* attn = (const float*)d_in[2];
    const void*  kptr = (const void*)d_in[3];

    float* hbuf = (float*)d_ws;                                   // 8192*64 fp32 = 2 MB
    float* outp = (float*)d_out;                                  // [8192][128]
    float* att_out = outp + (size_t)N_NODES * (CHEADS * OUT_F);   // [16384][8192]

    hipLaunchKernelGGL(h_kernel,    dim3(N_NODES / 4), dim3(BLK), 0, stream, x, W, hbuf);
    hipLaunchKernelGGL(topk_kernel, dim3(ROWS),        dim3(BLK), 0, stream, attn, hbuf, kptr, outp, att_out);
}